// Round 18
// baseline (325.263 us; speedup 1.0000x reference)
//
#include <hip/hip_runtime.h>
#include <hip/hip_bf16.h>
#include <math.h>

typedef unsigned short u16;
typedef unsigned char u8;
typedef __attribute__((ext_vector_type(8))) short bf16x8;
typedef __attribute__((ext_vector_type(4))) float f32x4;
typedef __attribute__((ext_vector_type(2))) float f32x2;
typedef _Float16 f16;
typedef __attribute__((ext_vector_type(2))) _Float16 f16x2;

#if __has_builtin(__builtin_amdgcn_cvt_pk_f32_fp8) && __has_builtin(__builtin_amdgcn_cvt_pk_fp8_f32)
#define HAS_FP8 1
#else
#define HAS_FP8 0
#endif

#if __has_builtin(__builtin_elementwise_fma)
#define VFMA(a, b, c) __builtin_elementwise_fma((a), (b), (c))
#else
#define VFMA(a, b, c) ((a) * (b) + (c))   // HIP default contracts to fma
#endif

__device__ __forceinline__ u16 f2bf(float f) {
    unsigned u = __float_as_uint(f);
    u += 0x7fffu + ((u >> 16) & 1u);   // RNE
    return (u16)(u >> 16);
}
__device__ __forceinline__ u16 f2h(float f) {
    return __builtin_bit_cast(u16, (f16)f);   // v_cvt_f16_f32 (RNE)
}
__device__ __forceinline__ f16x2 u2h(int u) {
    return __builtin_bit_cast(f16x2, u);
}
__device__ __forceinline__ f32x2 shfl_xor2(f32x2 v, int mask) {
    double d = __builtin_bit_cast(double, v);
    d = __shfl_xor(d, mask);
    return __builtin_bit_cast(f32x2, d);
}
__device__ __forceinline__ f32x2 mk2(float a, float b) {
    f32x2 r; r.x = a; r.y = b; return r;
}

// ---------------------------------------------------------------------------
// prep_misc: grid-partitioned fusion of {convert W1, convert W2, zero deg}.
// wt[832][64] bf16 (cols 0-255 q *0.125 folded, 256-511 k, 512-767 v,
// 768-831 s), bias ba[832] fp32 (q part *0.125).
// ---------------------------------------------------------------------------
__device__ __forceinline__ void conv_w_one(
    int idx,
    const float* __restrict__ Wq, const float* __restrict__ Wk,
    const float* __restrict__ Wv, const float* __restrict__ Ws,
    const float* __restrict__ bq, const float* __restrict__ bk,
    const float* __restrict__ bv, const float* __restrict__ bs,
    u16* __restrict__ wt, float* __restrict__ ba)
{
    int col = idx >> 6, k = idx & 63;
    float w;
    if      (col < 256) w = Wq[k * 256 + col] * 0.125f;          // fold 1/sqrt(C)
    else if (col < 512) w = Wk[k * 256 + (col - 256)];
    else if (col < 768) w = Wv[k * 256 + (col - 512)];
    else                w = Ws[k * 64  + (col - 768)];
    wt[col * 64 + k] = f2bf(w);
    if (k == 0)
        ba[col] = (col < 256) ? bq[col] * 0.125f : (col < 512) ? bk[col - 256]
                 : (col < 768) ? bv[col - 512] : bs[col - 768];
}

__global__ __launch_bounds__(256) void prep_misc(
    const float* __restrict__ Wq1, const float* __restrict__ Wk1,
    const float* __restrict__ Wv1, const float* __restrict__ Ws1,
    const float* __restrict__ bq1, const float* __restrict__ bk1,
    const float* __restrict__ bv1, const float* __restrict__ bs1,
    const float* __restrict__ Wq2, const float* __restrict__ Wk2,
    const float* __restrict__ Wv2, const float* __restrict__ Ws2,
    const float* __restrict__ bq2, const float* __restrict__ bk2,
    const float* __restrict__ bv2, const float* __restrict__ bs2,
    u16* __restrict__ wt1, float* __restrict__ ba1,
    u16* __restrict__ wt2, float* __restrict__ ba2,
    int* __restrict__ deg, int n)
{
    int b = blockIdx.x, t = threadIdx.x;
    if (b < 208) {
        conv_w_one(b * 256 + t, Wq1, Wk1, Wv1, Ws1, bq1, bk1, bv1, bs1, wt1, ba1);
    } else if (b < 416) {
        conv_w_one((b - 208) * 256 + t, Wq2, Wk2, Wv2, Ws2, bq2, bk2, bv2, bs2, wt2, ba2);
    } else {
        int i = (b - 416) * 256 + t;
        if (i < n) deg[i] = 0;
    }
}

// ---------------------------------------------------------------------------
// CSR scan (3-phase coalesced) + fill
// ---------------------------------------------------------------------------
__global__ __launch_bounds__(256) void scanA(
    const int* __restrict__ deg, int* __restrict__ bsum, int n)
{
    int i = blockIdx.x * 256 + threadIdx.x;
    int v = (i < n) ? deg[i] : 0;
    #pragma unroll
    for (int o = 32; o; o >>= 1) v += __shfl_xor(v, o);
    __shared__ int wsum[4];
    if ((threadIdx.x & 63) == 0) wsum[threadIdx.x >> 6] = v;
    __syncthreads();
    if (threadIdx.x == 0)
        bsum[blockIdx.x] = wsum[0] + wsum[1] + wsum[2] + wsum[3];
}

__global__ __launch_bounds__(256) void scanB(
    const int* __restrict__ bsum, int* __restrict__ bpre, int nb)
{
    int t = threadIdx.x;
    int v = (t < nb) ? bsum[t] : 0;
    int lane = t & 63, wv = t >> 6;
    int sv = v;
    #pragma unroll
    for (int o = 1; o < 64; o <<= 1) {
        int u = __shfl_up(sv, o);
        if (lane >= o) sv += u;
    }
    __shared__ int wsum[4];
    if (lane == 63) wsum[wv] = sv;
    __syncthreads();
    int add = 0;
    for (int k = 0; k < wv; ++k) add += wsum[k];
    if (t < nb) bpre[t] = sv + add - v;   // exclusive
}

__global__ __launch_bounds__(256) void scanC(
    const int* __restrict__ deg, const int* __restrict__ bpre,
    int* __restrict__ off, int* __restrict__ cursor, int n, int E)
{
    int i = blockIdx.x * 256 + threadIdx.x;
    int v = (i < n) ? deg[i] : 0;
    int lane = threadIdx.x & 63, wv = threadIdx.x >> 6;
    int sv = v;
    #pragma unroll
    for (int o = 1; o < 64; o <<= 1) {
        int u = __shfl_up(sv, o);
        if (lane >= o) sv += u;
    }
    __shared__ int wsum[4];
    if (lane == 63) wsum[wv] = sv;
    __syncthreads();
    int add = bpre[blockIdx.x];
    for (int k = 0; k < wv; ++k) add += wsum[k];
    int excl = add + sv - v;
    if (i < n) {
        off[i] = excl; cursor[i] = excl;
        if (i == n - 1) off[n] = E;
    }
}

__global__ __launch_bounds__(256) void fill_kernel(
    const int* __restrict__ src, const int* __restrict__ dst,
    int* __restrict__ cursor, int* __restrict__ csr_src, int E)
{
    int e = blockIdx.x * 256 + threadIdx.x;
    if (e >= E) return;
    int slot = atomicAdd(&cursor[dst[e]], 1);
    csr_src[slot] = src[e];
}

// ---------------------------------------------------------------------------
// bf16 MFMA GEMM body: 32 nodes/block (two B-fragment groups share the same
// A/wt fragments). Each lane owns 4 consecutive output cols. q f16; k,v fp8
// INTERLEAVED in kvb (per node: 32 lane-groups x {8B k, 8B v}); skip f16.
// ---------------------------------------------------------------------------
template <int FP32IN>
__device__ __forceinline__ void gemm_body(
    int blk, const void* __restrict__ Xv, const u16* __restrict__ wt,
    const float* __restrict__ ba,
    u16* __restrict__ qb, u8* __restrict__ kvb, u16* __restrict__ skip, int n)
{
    const int w = threadIdx.x >> 6, lane = threadIdx.x & 63;
    const int r = lane & 15, g = lane >> 4;
    const int node0 = blk * 32;

    bf16x8 bx0[2], bx1[2];                    // X fragments, 2 node groups
    #pragma unroll
    for (int grp = 0; grp < 2; ++grp) {
        int nr = node0 + grp * 16 + r; if (nr >= n) nr = n - 1;
        if (FP32IN) {
            const float* xr = (const float*)Xv + (size_t)nr * 64 + g * 8;
            float t0[8], t1[8];
            *(float4*)(t0)     = ((const float4*)xr)[0];
            *(float4*)(t0 + 4) = ((const float4*)xr)[1];
            *(float4*)(t1)     = ((const float4*)(xr + 32))[0];
            *(float4*)(t1 + 4) = ((const float4*)(xr + 32))[1];
            #pragma unroll
            for (int j = 0; j < 8; ++j) {
                bx0[grp][j] = (short)f2bf(t0[j]);
                bx1[grp][j] = (short)f2bf(t1[j]);
            }
        } else {
            const u16* xr = (const u16*)Xv + (size_t)nr * 64 + g * 8;
            bx0[grp] = *(const bf16x8*)xr;
            bx1[grp] = *(const bf16x8*)(xr + 32);
        }
    }

    const int colbase = w * 208;

    const u16* wr0 = wt + (size_t)(colbase + r) * 64 + g * 8;
    bf16x8 a0 = *(const bf16x8*)wr0;
    bf16x8 a1 = *(const bf16x8*)(wr0 + 32);

    for (int ct = 0; ct < 13; ++ct) {
        int ctn = (ct + 1 < 13) ? ct + 1 : 12;
        const u16* wrn = wt + (size_t)(colbase + ctn * 16 + r) * 64 + g * 8;
        bf16x8 an0 = *(const bf16x8*)wrn;
        bf16x8 an1 = *(const bf16x8*)(wrn + 32);

        int col0 = colbase + ct * 16 + g * 4;
        float4 bias = *(const float4*)(ba + col0);

        #pragma unroll
        for (int grp = 0; grp < 2; ++grp) {
            f32x4 acc = {0.f, 0.f, 0.f, 0.f};
            acc = __builtin_amdgcn_mfma_f32_16x16x32_bf16(a0, bx0[grp], acc, 0, 0, 0);
            acc = __builtin_amdgcn_mfma_f32_16x16x32_bf16(a1, bx1[grp], acc, 0, 0, 0);
            int node = node0 + grp * 16 + r;
            if (node < n) {
                float v0 = acc[0] + bias.x, v1 = acc[1] + bias.y;
                float v2 = acc[2] + bias.z, v3 = acc[3] + bias.w;
                if (col0 < 256) {
                    ushort4 o;
                    o.x = f2h(v0); o.y = f2h(v1); o.z = f2h(v2); o.w = f2h(v3);
                    *(ushort4*)(qb + (size_t)node * 256 + col0) = o;
                } else if (col0 < 768) {
                    const bool isK = col0 < 512;
                    int c = col0 - (isK ? 256 : 512);
#if HAS_FP8
                    unsigned pk = __builtin_amdgcn_cvt_pk_fp8_f32(v0, v1, 0u, false);
                    pk = __builtin_amdgcn_cvt_pk_fp8_f32(v2, v3, pk, true);
                    *(unsigned*)(kvb + (size_t)node * 512 + ((c >> 3) << 4)
                                 + (c & 7) + (isK ? 0 : 8)) = pk;
#else
                    ushort4 o;
                    o.x = f2h(v0); o.y = f2h(v1); o.z = f2h(v2); o.w = f2h(v3);
                    *(ushort4*)(kvb + (size_t)node * 1024 + ((c >> 3) << 5)
                                + ((c & 7) << 1) + (isK ? 0 : 16)) = o;
#endif
                } else {
                    ushort4 o;
                    o.x = f2h(v0); o.y = f2h(v1); o.z = f2h(v2); o.w = f2h(v3);
                    *(ushort4*)(skip + (size_t)node * 64 + (col0 - 768)) = o;
                }
            }
        }
        a0 = an0; a1 = an1;
    }
}

// gemm1 fused with degree histogram (both depend only on prep_misc)
__global__ __launch_bounds__(256) void gemm1_hist(
    const float* __restrict__ x, const u16* __restrict__ wt,
    const float* __restrict__ ba,
    u16* __restrict__ qb, u8* __restrict__ kvb, u16* __restrict__ skip, int n,
    const int* __restrict__ dst, int* __restrict__ deg, int E, int gb)
{
    int b = blockIdx.x;
    if (b < gb) {
        gemm_body<1>(b, x, wt, ba, qb, kvb, skip, n);
    } else {
        int e = (b - gb) * 256 + threadIdx.x;
        if (e < E) atomicAdd(&deg[dst[e]], 1);
    }
}

__global__ __launch_bounds__(256) void gemm_qkvs2(
    const u16* __restrict__ xbf, const u16* __restrict__ wt,
    const float* __restrict__ ba,
    u16* __restrict__ qb, u8* __restrict__ kvb, u16* __restrict__ skip, int n)
{
    gemm_body<0>(blockIdx.x, xbf, wt, ba, qb, kvb, skip, n);
}

// ---------------------------------------------------------------------------
// Fused attention: ONE node per wave, TWO edge-streams (half-wave each,
// edges t = 2i+half). Interleaved fp8 kv: ONE dwordx4 gather per lane per
// iteration. NO online max: logits are O(6 sigma) << fp32 exp range, so
// l += exp(p), a += exp(p)*v directly (identical softmax result). Packed
// f32x2 math; clamped 3-deep prefetch ring under #pragma unroll 3.
// FINAL: fuse LayerNorm output through LDS into the 64->32 matvec (d_out).
// ---------------------------------------------------------------------------
template <int RELU, int BF16OUT, int FINAL>
__global__ __launch_bounds__(256) void fused_attn(
    const u16* __restrict__ qb, const u8* __restrict__ kvb,
    const u16* __restrict__ skip,
    const int* __restrict__ off, const int* __restrict__ csr,
    const float* __restrict__ lng, const float* __restrict__ lnb,
    u16* __restrict__ out_bf,
    const float* __restrict__ Wf, const float* __restrict__ bfv,
    float* __restrict__ outF, int n)
{
    const int lane = threadIdx.x & 63;
    const int half = lane >> 5;          // edge-stream parity
    const int hl   = lane & 31;          // h*8 + c8
    const int c8   = lane & 7;
    const int wv   = threadIdx.x >> 6;
    const int node = blockIdx.x * 4 + wv;
    const bool nvalid = node < n;
    const int nodeC = nvalid ? node : n - 1;

    // q: decode f16 row slice to packed f32x2 (1/sqrt(C) pre-folded into Wq)
    const int4 qw = *(const int4*)(qb + (size_t)nodeC * 256 + hl * 8);
    f32x2 q01, q23, q45, q67;
    {
        f16x2 t0 = u2h(qw.x), t1 = u2h(qw.y), t2 = u2h(qw.z), t3 = u2h(qw.w);
        q01 = mk2((float)t0.x, (float)t0.y);
        q23 = mk2((float)t1.x, (float)t1.y);
        q45 = mk2((float)t2.x, (float)t2.y);
        q67 = mk2((float)t3.x, (float)t3.y);
    }

    const int s0 = off[nodeC], s1 = off[nodeC + 1];
    const int deg = nvalid ? (s1 - s0) : 0;
    const int imax = (deg + 1) >> 1;     // iterations per stream

    float l = 0.f;
    f32x2 a01 = mk2(0.f, 0.f), a23 = mk2(0.f, 0.f);
    f32x2 a45 = mk2(0.f, 0.f), a67 = mk2(0.f, 0.f);

    if (imax > 0) {
#if HAS_FP8
        const u8* kvbase = kvb + hl * 16;
        // clamped: tail loads re-read row csr[s1-1] (cache-hot, masked out)
        #define LOADKV(I, KV) { \
            int _ix = min(s0 + 2 * (I) + half, s1 - 1); \
            int _s = csr[_ix]; \
            KV = *(const uint4*)(kvbase + (size_t)_s * 512); }

        uint4 kv0, kv1, kv2;
        LOADKV(0, kv0);
        LOADKV(1, kv1);
        LOADKV(2, kv2);

        #pragma unroll 3
        for (int i = 0; i < imax; ++i) {
            uint4 kvn;
            LOADKV(i + 3, kvn);

            f32x2 k01 = __builtin_amdgcn_cvt_pk_f32_fp8(kv0.x, false);
            f32x2 k23 = __builtin_amdgcn_cvt_pk_f32_fp8(kv0.x, true);
            f32x2 k45 = __builtin_amdgcn_cvt_pk_f32_fp8(kv0.y, false);
            f32x2 k67 = __builtin_amdgcn_cvt_pk_f32_fp8(kv0.y, true);
            f32x2 pp = k01 * q01;
            pp = VFMA(k23, q23, pp);
            pp = VFMA(k45, q45, pp);
            pp = VFMA(k67, q67, pp);
            float p = pp.x + pp.y;
            p += __shfl_xor(p, 1);
            p += __shfl_xor(p, 2);
            p += __shfl_xor(p, 4);
            p = (2 * i + half < deg) ? p : -2e30f;   // tail mask -> exp = 0

            f32x2 w01 = __builtin_amdgcn_cvt_pk_f32_fp8(kv0.z, false);
            f32x2 w23 = __builtin_amdgcn_cvt_pk_f32_fp8(kv0.z, true);
            f32x2 w45 = __builtin_amdgcn_cvt_pk_f32_fp8(kv0.w, false);
            f32x2 w67 = __builtin_amdgcn_cvt_pk_f32_fp8(kv0.w, true);
            float e = __expf(p);
            l += e;
            f32x2 e2 = mk2(e, e);
            a01 = VFMA(e2, w01, a01);
            a23 = VFMA(e2, w23, a23);
            a45 = VFMA(e2, w45, a45);
            a67 = VFMA(e2, w67, a67);

            kv0 = kv1; kv1 = kv2; kv2 = kvn;
        }
        #undef LOADKV
#else
        const u8* kvbase = kvb + hl * 32;
        #define LOADKV(I, K, V) { \
            int _ix = min(s0 + 2 * (I) + half, s1 - 1); \
            int _s = csr[_ix]; \
            K = *(const int4*)(kvbase + (size_t)_s * 1024); \
            V = *(const int4*)(kvbase + (size_t)_s * 1024 + 16); }

        int4 k0, k1, k2, v0, v1, v2;
        LOADKV(0, k0, v0);
        LOADKV(1, k1, v1);
        LOADKV(2, k2, v2);

        #pragma unroll 3
        for (int i = 0; i < imax; ++i) {
            int4 kn, vn;
            LOADKV(i + 3, kn, vn);

            f16x2 t0 = u2h(k0.x), t1 = u2h(k0.y), t2 = u2h(k0.z), t3 = u2h(k0.w);
            f32x2 k01 = mk2((float)t0.x, (float)t0.y);
            f32x2 k23 = mk2((float)t1.x, (float)t1.y);
            f32x2 k45 = mk2((float)t2.x, (float)t2.y);
            f32x2 k67 = mk2((float)t3.x, (float)t3.y);
            f32x2 pp = k01 * q01;
            pp = VFMA(k23, q23, pp);
            pp = VFMA(k45, q45, pp);
            pp = VFMA(k67, q67, pp);
            float p = pp.x + pp.y;
            p += __shfl_xor(p, 1);
            p += __shfl_xor(p, 2);
            p += __shfl_xor(p, 4);
            p = (2 * i + half < deg) ? p : -2e30f;

            f16x2 s0v = u2h(v0.x), s1v = u2h(v0.y), s2v = u2h(v0.z), s3v = u2h(v0.w);
            f32x2 w01 = mk2((float)s0v.x, (float)s0v.y);
            f32x2 w23 = mk2((float)s1v.x, (float)s1v.y);
            f32x2 w45 = mk2((float)s2v.x, (float)s2v.y);
            f32x2 w67 = mk2((float)s3v.x, (float)s3v.y);
            float e = __expf(p);
            l += e;
            f32x2 e2 = mk2(e, e);
            a01 = VFMA(e2, w01, a01);
            a23 = VFMA(e2, w23, a23);
            a45 = VFMA(e2, w45, a45);
            a67 = VFMA(e2, w67, a67);

            k0 = k1; v0 = v1; k1 = k2; v1 = v2; k2 = kn; v2 = vn;
        }
        #undef LOADKV
#endif
    }

    // merge the two streams (lane ^ 32 holds the partner state): plain sums
    l += __shfl_xor(l, 32);
    a01 = a01 + shfl_xor2(a01, 32);
    a23 = a23 + shfl_xor2(a23, 32);
    a45 = a45 + shfl_xor2(a45, 32);
    a67 = a67 + shfl_xor2(a67, 32);

    // normalize per head, then mean over heads (hl bits 3,4)
    {
        const float inv = 0.25f / (l + 1e-16f);
        f32x2 inv2 = mk2(inv, inv);
        a01 *= inv2; a23 *= inv2; a45 *= inv2; a67 *= inv2;
        a01 = a01 + shfl_xor2(a01, 8);  a01 = a01 + shfl_xor2(a01, 16);
        a23 = a23 + shfl_xor2(a23, 8);  a23 = a23 + shfl_xor2(a23, 16);
        a45 = a45 + shfl_xor2(a45, 8);  a45 = a45 + shfl_xor2(a45, 16);
        a67 = a67 + shfl_xor2(a67, 8);  a67 = a67 + shfl_xor2(a67, 16);
    }

    // skip connection (f16): channels c8*8 .. +7
    const int4 skw = *(const int4*)(skip + (size_t)nodeC * 64 + c8 * 8);
    f16x2 s0_ = u2h(skw.x), s1_ = u2h(skw.y), s2_ = u2h(skw.z), s3_ = u2h(skw.w);
    f32x2 o01 = a01 + mk2((float)s0_.x, (float)s0_.y);
    f32x2 o23 = a23 + mk2((float)s1_.x, (float)s1_.y);
    f32x2 o45 = a45 + mk2((float)s2_.x, (float)s2_.y);
    f32x2 o67 = a67 + mk2((float)s3_.x, (float)s3_.y);

    // LayerNorm over 64 channels (8 lanes x 8 ch within each 8-lane group)
    f32x2 ss = o01 + o23 + o45 + o67;
    float s = ss.x + ss.y;
    s += __shfl_xor(s, 1); s += __shfl_xor(s, 2); s += __shfl_xor(s, 4);
    const float mu = s * (1.f / 64.f);
    f32x2 mu2 = mk2(mu, mu);
    o01 -= mu2; o23 -= mu2; o45 -= mu2; o67 -= mu2;
    f32x2 vv = o01 * o01;
    vv = VFMA(o23, o23, vv);
    vv = VFMA(o45, o45, vv);
    vv = VFMA(o67, o67, vv);
    float vs = vv.x + vv.y;
    vs += __shfl_xor(vs, 1); vs += __shfl_xor(vs, 2); vs += __shfl_xor(vs, 4);
    const float rs = rsqrtf(vs * (1.f / 64.f) + 1e-5f);
    f32x2 rs2 = mk2(rs, rs);

    const float4* gp = (const float4*)(lng + c8 * 8);
    const float4* bp = (const float4*)(lnb + c8 * 8);
    float4 g0 = gp[0], g1 = gp[1], b0 = bp[0], b1 = bp[1];
    f32x2 g01 = mk2(g0.x, g0.y), g23 = mk2(g0.z, g0.w);
    f32x2 g45 = mk2(g1.x, g1.y), g67 = mk2(g1.z, g1.w);
    f32x2 bb01 = mk2(b0.x, b0.y), bb23 = mk2(b0.z, b0.w);
    f32x2 bb45 = mk2(b1.x, b1.y), bb67 = mk2(b1.z, b1.w);
    f32x2 y01 = VFMA(o01 * rs2, g01, bb01);
    f32x2 y23 = VFMA(o23 * rs2, g23, bb23);
    f32x2 y45 = VFMA(o45 * rs2, g45, bb45);
    f32x2 y67 = VFMA(o67 * rs2, g67, bb67);
    if (RELU) {
        y01 = mk2(fmaxf(y01.x, 0.f), fmaxf(y01.y, 0.f));
        y23 = mk2(fmaxf(y23.x, 0.f), fmaxf(y23.y, 0.f));
        y45 = mk2(fmaxf(y45.x, 0.f), fmaxf(y45.y, 0.f));
        y67 = mk2(fmaxf(y67.x, 0.f), fmaxf(y67.y, 0.f));
    }

    if (FINAL) {
        // fused 64->32 matvec via LDS (y of 4 nodes staged per block)
        __shared__ float yl[4][64];
        if (lane < 8) {
            float* dst = &yl[wv][c8 * 8];
            *(float2*)(dst + 0) = make_float2(y01.x, y01.y);
            *(float2*)(dst + 2) = make_float2(y23.x, y23.y);
            *(float2*)(dst + 4) = make_float2(y45.x, y45.y);
            *(float2*)(dst + 6) = make_float2(y67.x, y67.y);
        }
        __syncthreads();
        int t = threadIdx.x;
        if (t < 128) {
            int nd = t >> 5, oc = t & 31;
            int gn = blockIdx.x * 4 + nd;
            if (gn < n) {
                float acc = bfv[oc];
                #pragma unroll
                for (int c = 0; c < 64; ++c)
                    acc = fmaf(yl[nd][c], Wf[c * 32 + oc], acc);
                outF[(size_t)gn * 32 + oc] = acc;
            }
        }
    } else if (lane < 8 && nvalid) {
        if (BF16OUT) {
            bf16x8 ob;
            ob[0] = (short)f2bf(y01.x); ob[1] = (short)f2bf(y01.y);
            ob[2] = (short)f2bf(y23.x); ob[3] = (short)f2bf(y23.y);
            ob[4] = (short)f2bf(y45.x); ob[5] = (short)f2bf(y45.y);
            ob[6] = (short)f2bf(y67.x); ob[7] = (short)f2bf(y67.y);
            *(bf16x8*)(out_bf + (size_t)node * 64 + c8 * 8) = ob;
        }
    }
}

// ---------------------------------------------------------------------------
extern "C" void kernel_launch(void* const* d_in, const int* in_sizes, int n_in,
                              void* d_out, int out_size, void* d_ws, size_t ws_size,
                              hipStream_t stream)
{
    const float* x   = (const float*)d_in[0];
    const int*   ei  = (const int*)d_in[1];
    const float* Wq1 = (const float*)d_in[2];  const float* bq1 = (const float*)d_in[3];
    const float* Wk1 = (const float*)d_in[4];  const float* bk1 = (const float*)d_in[5];
    const float* Wv1 = (const float*)d_in[6];  const float* bv1 = (const float*)d_in[7];
    const float* Ws1 = (const float*)d_in[8];  const float* bs1 = (const float*)d_in[9];
    const float* Wq2 = (const float*)d_in[10]; const float* bq2 = (const float*)d_in[11];
    const float* Wk2 = (const float*)d_in[12]; const float* bk2 = (const float*)d_in[13];
    const float* Wv2 = (const float*)d_in[14]; const float* bv2 = (const float*)d_in[15];
    const float* Ws2 = (const float*)d_in[16]; const float* bs2 = (const float*)d_in[17];
    const float* lng = (const float*)d_in[18]; const float* lnb = (const float*)d_in[19];
    const float* Wf  = (const float*)d_in[20]; const float* bf  = (const float*)d_in[21];

    const int N = in_sizes[0] / 64;
    const int E = in_sizes[1] / 2;
    const int* src  = ei;
    const int* dstp = ei + E;

    char* p = (char*)d_ws;
    u16* qb   = (u16*)p; p += (size_t)N * 256 * 2;   // f16
    u8*  kvb  = (u8*)p;  p += (size_t)N * 1024;      // fp8 interleaved (f16 fallback fits)
    u16* xbf  = (u16*)p; p += (size_t)N * 64 * 2;    // conv1 output h (bf16)
    u16* wt1  = (u16*)p; p += 832 * 64 * 2;
    u16* wt2  = (u16*)p; p += 832 * 64 * 2;
    float* ba1  = (float*)p; p += 832 * 4;
    float* ba2  = (float*)p; p += 832 * 4;
    u16* skip = (u16*)p; p += (size_t)N * 64 * 2;    // f16
    int* deg    = (int*)p; p += (size_t)N * 4;
    int* off    = (int*)p; p += ((size_t)N + 1) * 4;
    int* cursor = (int*)p; p += (size_t)N * 4;
    int* csr    = (int*)p; p += (size_t)E * 4;
    int* bsum   = (int*)p; p += 1024;
    int* bpre   = (int*)p; p += 1024;

    const int e_blocks    = (E + 255) / 256;
    const int n_blocks    = (N + 255) / 256;
    const int prep_blocks = 416 + n_blocks;
    const int gb          = (N + 31) / 32;          // 32 nodes/block
    const int attn_blocks = (N + 3) / 4;            // 1 node/wave, 4 waves/blk

    // ---- prep: fused conversions + zero deg ----
    prep_misc<<<prep_blocks, 256, 0, stream>>>(
        Wq1, Wk1, Wv1, Ws1, bq1, bk1, bv1, bs1,
        Wq2, Wk2, Wv2, Ws2, bq2, bk2, bv2, bs2,
        wt1, ba1, wt2, ba2, deg, N);

    // ---- conv1 GEMM + degree histogram (fused, both only need prep) ----
    gemm1_hist<<<gb + e_blocks, 256, 0, stream>>>(
        x, wt1, ba1, qb, kvb, skip, N, dstp, deg, E, gb);

    // ---- CSR scan + fill ----
    scanA<<<n_blocks, 256, 0, stream>>>(deg, bsum, N);
    scanB<<<1, 256, 0, stream>>>(bsum, bpre, n_blocks);
    scanC<<<n_blocks, 256, 0, stream>>>(deg, bpre, off, cursor, N, E);
    fill_kernel<<<e_blocks, 256, 0, stream>>>(src, dstp, cursor, csr, E);

    // ---- conv1 attention (writes h bf16) ----
    fused_attn<1, 1, 0><<<attn_blocks, 256, 0, stream>>>(
        qb, kvb, skip, off, csr, lng, lnb, xbf, nullptr, nullptr, nullptr, N);

    // ---- conv2 GEMM ----
    gemm_qkvs2<<<gb, 256, 0, stream>>>(xbf, wt2, ba2, qb, kvb, skip, N);

    // ---- conv2 attention + fused final LN/Linear -> d_out ----
    fused_attn<0, 0, 1><<<attn_blocks, 256, 0, stream>>>(
        qb, kvb, skip, off, csr, lng, lnb, nullptr, Wf, bf, (float*)d_out, N);
}